// Round 1
// baseline (838.314 us; speedup 1.0000x reference)
//
#include <hip/hip_runtime.h>

// Problem constants (fixed by the reference)
#define B_    128
#define L_    1024
#define DK_   128
#define DV_   256
#define NS_   50      // N memory slots
#define H_    256
#define M_    (B_ * L_)   // 131072 rows

typedef __attribute__((ext_vector_type(8))) short   short8;
typedef __attribute__((ext_vector_type(4))) float   float4v;
typedef __attribute__((ext_vector_type(4))) int     int4v;

__device__ __forceinline__ float b2f(unsigned short u) {
    unsigned int x = ((unsigned int)u) << 16;
    return __builtin_bit_cast(float, x);
}
__device__ __forceinline__ unsigned short f2b(float f) {
    unsigned int x = __builtin_bit_cast(unsigned int, f);
    x += 0x7fffu + ((x >> 16) & 1u);   // round-to-nearest-even
    return (unsigned short)(x >> 16);
}
__device__ __forceinline__ int pack2(float lo, float hi) {
    return (int)f2b(lo) | ((int)f2b(hi) << 16);
}
__device__ __forceinline__ float sigmoid_f(float x) {
    return 1.f / (1.f + __expf(-x));
}
__device__ __forceinline__ float tanh_f(float x) {
    return 1.f - 2.f / (__expf(2.f * x) + 1.f);  // safe at exp overflow
}

// async global -> LDS, 16B per lane (wave-uniform LDS base; HW adds lane*16)
__device__ __forceinline__ void gload_lds16(const void* g, void* l) {
    __builtin_amdgcn_global_load_lds(
        (const __attribute__((address_space(1))) void*)g,
        (__attribute__((address_space(3))) void*)l, 16, 0, 0);
}

// ---------------------------------------------------------------------------
// Gate kernel: e = sigmoid(X We^T + be), a = tanh(X Wa^T + ba)
// X: (M_,256) fp32. We/Wa: (256,256) fp32 row-major [out][in] = B^T layout.
// Outputs bf16. grid (M_/128, 2, 2)  block 256
// ---------------------------------------------------------------------------
__global__ __launch_bounds__(256) void gate_kernel(
    const float* __restrict__ X,
    const float* __restrict__ We, const float* __restrict__ be,
    const float* __restrict__ Wa, const float* __restrict__ ba,
    unsigned short* __restrict__ e_out, unsigned short* __restrict__ a_out)
{
    constexpr int K = DV_;  // 256
    const int mblk = blockIdx.x, nblk = blockIdx.y, gate = blockIdx.z;
    const float* W    = gate ? Wa : We;
    const float* bias = gate ? ba : be;
    unsigned short* out = gate ? a_out : e_out;

    __shared__ unsigned short As[128 * 40];  // +8 pad per row
    __shared__ unsigned short Bs[128 * 40];

    const int tid  = threadIdx.x;
    const int lane = tid & 63, wid = tid >> 6;
    const int wm = wid >> 1, wn = wid & 1;
    const int l15 = lane & 15, quad = lane >> 4;

    float4v acc[4][4];
#pragma unroll
    for (int i = 0; i < 4; i++)
#pragma unroll
        for (int j = 0; j < 4; j++) {
            acc[i][j][0] = 0.f; acc[i][j][1] = 0.f;
            acc[i][j][2] = 0.f; acc[i][j][3] = 0.f;
        }

    const int srow = tid >> 1;          // 0..127
    const int scol = (tid & 1) * 16;    // 0 or 16 (bf16 element units)
    const size_t Abase = ((size_t)mblk * 128 + srow) * K;
    const size_t Bbase = ((size_t)nblk * 128 + srow) * K;

    for (int k0 = 0; k0 < K; k0 += 32) {
        const float* xa = &X[Abase + k0 + scol];
        const float* xb = &W[Bbase + k0 + scol];
        int4v pa0, pa1, pb0, pb1;
#pragma unroll
        for (int j = 0; j < 4; j++) {
            pa0[j] = pack2(xa[2*j],     xa[2*j + 1]);
            pa1[j] = pack2(xa[2*j + 8], xa[2*j + 9]);
            pb0[j] = pack2(xb[2*j],     xb[2*j + 1]);
            pb1[j] = pack2(xb[2*j + 8], xb[2*j + 9]);
        }
        *(int4v*)&As[srow * 40 + scol]     = pa0;
        *(int4v*)&As[srow * 40 + scol + 8] = pa1;
        *(int4v*)&Bs[srow * 40 + scol]     = pb0;
        *(int4v*)&Bs[srow * 40 + scol + 8] = pb1;
        __syncthreads();
        short8 af[4], bf[4];
#pragma unroll
        for (int i = 0; i < 4; i++)
            af[i] = *(const short8*)&As[(64 * wm + 16 * i + l15) * 40 + quad * 8];
#pragma unroll
        for (int j = 0; j < 4; j++)
            bf[j] = *(const short8*)&Bs[(64 * wn + 16 * j + l15) * 40 + quad * 8];
#pragma unroll
        for (int i = 0; i < 4; i++)
#pragma unroll
            for (int j = 0; j < 4; j++)
                acc[i][j] = __builtin_amdgcn_mfma_f32_16x16x32_bf16(af[i], bf[j], acc[i][j], 0, 0, 0);
        __syncthreads();
    }

#pragma unroll
    for (int i = 0; i < 4; i++) {
        const int row = mblk * 128 + 64 * wm + 16 * i + quad * 4;
#pragma unroll
        for (int j = 0; j < 4; j++) {
            const int col = nblk * 128 + 64 * wn + 16 * j + l15;
            const float bv = bias[col];
#pragma unroll
            for (int r = 0; r < 4; r++) {
                float v = acc[i][j][r] + bv;
                v = gate ? tanh_f(v) : sigmoid_f(v);
                out[(size_t)(row + r) * DV_ + col] = f2b(v);
            }
        }
    }
}

// ---------------------------------------------------------------------------
// Score kernel: score = softmax(P Wk^T) over 50 slots. Thread per row. fp32.
// Emits scan-friendly layout: (B, L, 4, 16) fp32, slot n = ng*13+i at
// [ng*16 + i] for i<13 (and n<50); padding zeros elsewhere.
// grid 512, block 256
// ---------------------------------------------------------------------------
__global__ __launch_bounds__(256) void score_kernel(
    const float* __restrict__ problems,  // (M_,128)
    const float* __restrict__ w_key,     // (50,128)
    float* __restrict__ score_scan)      // (M_,64)
{
    const int rowi = blockIdx.x * 256 + threadIdx.x;
    const float* p = problems + (size_t)rowi * DK_;

    float logit[NS_];
#pragma unroll
    for (int n = 0; n < NS_; n++) logit[n] = 0.f;

    for (int k0 = 0; k0 < DK_; k0 += 4) {
        float pf0 = p[k0], pf1 = p[k0+1], pf2 = p[k0+2], pf3 = p[k0+3];
#pragma unroll
        for (int n = 0; n < NS_; n++) {
            const float* wk = &w_key[n * DK_ + k0];   // wave-uniform -> s_load
            logit[n] += pf0 * wk[0] + pf1 * wk[1] + pf2 * wk[2] + pf3 * wk[3];
        }
    }

    float mx = logit[0];
#pragma unroll
    for (int n = 1; n < NS_; n++) mx = fmaxf(mx, logit[n]);
    float sum = 0.f;
#pragma unroll
    for (int n = 0; n < NS_; n++) { logit[n] = __expf(logit[n] - mx); sum += logit[n]; }
    const float inv = 1.f / sum;

    float* o = score_scan + (size_t)rowi * 64;
#pragma unroll
    for (int v = 0; v < 16; v++) {
        float4v st;
#pragma unroll
        for (int c = 0; c < 4; c++) {
            const int j  = v * 4 + c;
            const int ng = j >> 4, ii = j & 15;
            const int n  = ng * 13 + ii;
            st[c] = (ii < 13 && n < NS_) ? logit[n] * inv : 0.f;
        }
        *(float4v*)(o + v * 4) = st;
    }
}

// ---------------------------------------------------------------------------
// Scan kernel v3: chunked double-buffered LDS staging via global_load_lds.
// Lane decomposition unchanged from v2: lane = dsub(0..15) + 16*ng(0..3),
// 13 slots/lane, read-before-update, shfl-xor reduce across ng.
// Chunk T=64 timesteps: score 16KB + e 8KB + a 8KB per buffer, x2 = 64KB LDS.
// grid (4, 128)  block 256.
// ---------------------------------------------------------------------------
#define TCH 64
#define NCH (L_ / TCH)   // 16

__global__ __launch_bounds__(256) void scan_kernel(
    const float* __restrict__ score_scan,         // (M_,64) fp32, zero-padded
    const unsigned short* __restrict__ e_buf,     // (M_,256) bf16
    const unsigned short* __restrict__ a_buf,     // (M_,256) bf16
    const float* __restrict__ init_mem,           // (50,256) fp32
    unsigned short* __restrict__ reads)           // (M_,256) bf16
{
    __shared__ float          score_s[2][TCH][64];   // 2 x 16 KB
    __shared__ unsigned short e_s[2][TCH][64];       // 2 x  8 KB
    __shared__ unsigned short a_s[2][TCH][64];       // 2 x  8 KB

    const int b    = blockIdx.y;
    const int dblk = blockIdx.x;          // 0..3
    const int tid  = threadIdx.x;
    const int w    = tid >> 6;
    const int lane = tid & 63;
    const int dsub = lane & 15;
    const int ng   = lane >> 4;
    const int d    = dblk * 64 + w * 16 + dsub;

    float M[13];
#pragma unroll
    for (int i = 0; i < 13; i++) {
        const int n = ng * 13 + i;
        M[i] = (n < NS_) ? init_mem[n * DV_ + d] : 0.f;
    }

    const size_t rb = (size_t)b * L_;
    // staging lane roles (wave covers 16 timesteps per buffer region)
    const int l4  = lane >> 4;    // score: 4 rows per 1KB instr
    const int c16 = lane & 15;    // score: 16B column (4 floats)
    const int l8  = lane >> 3;    // e/a: 8 rows per 1KB instr
    const int c8  = lane & 7;     // e/a: 16B column (8 bf16)

    auto stage = [&](int c, int p) {
        const int t0 = c * TCH + w * 16;
        // score: 64 t x 256B -> 16 instrs, 4 per wave (4 rows each)
#pragma unroll
        for (int i = 0; i < 4; i++) {
            const int tt = t0 + i * 4 + l4;
            gload_lds16(score_scan + ((rb + tt) * 64 + c16 * 4),
                        &score_s[p][w * 16 + i * 4][0]);
        }
        // e/a: 64 t x 128B -> 8 instrs each, 2 per wave (8 rows each)
#pragma unroll
        for (int i = 0; i < 2; i++) {
            const int tt = t0 + i * 8 + l8;
            gload_lds16(e_buf + ((rb + tt) * DV_ + dblk * 64 + c8 * 8),
                        &e_s[p][w * 16 + i * 8][0]);
            gload_lds16(a_buf + ((rb + tt) * DV_ + dblk * 64 + c8 * 8),
                        &a_s[p][w * 16 + i * 8][0]);
        }
    };

    unsigned short* rp = reads + rb * DV_ + d;

    int p = 0;
    stage(0, 0);
    asm volatile("s_waitcnt vmcnt(0)" ::: "memory");
    __syncthreads();

    for (int c = 0; c < NCH; ++c) {
        if (c + 1 < NCH) stage(c + 1, p ^ 1);   // in flight during compute

#pragma unroll 2
        for (int tt = 0; tt < TCH; ++tt) {
            const float* sc = &score_s[p][tt][ng * 16];
            const float4v s0 = *(const float4v*)(sc);
            const float4v s1 = *(const float4v*)(sc + 4);
            const float4v s2 = *(const float4v*)(sc + 8);
            const float   s3 = sc[12];
            const float e_cur = b2f(e_s[p][tt][w * 16 + dsub]);
            const float a_cur = b2f(a_s[p][tt][w * 16 + dsub]);

            float r = 0.f;
            const float sarr[13] = { s0[0], s0[1], s0[2], s0[3],
                                     s1[0], s1[1], s1[2], s1[3],
                                     s2[0], s2[1], s2[2], s2[3], s3 };
#pragma unroll
            for (int i = 0; i < 13; i++) {
                const float s = sarr[i];
                r = fmaf(s, M[i], r);                       // read BEFORE update
                M[i] = fmaf(s, fmaf(-e_cur, M[i], a_cur), M[i]);
            }
            // reduce partial reads across the 4 n-groups (lanes differ in bits 4,5)
            r += __shfl_xor(r, 16);
            r += __shfl_xor(r, 32);
            if (ng == 0) rp[(size_t)(c * TCH + tt) * DV_] = f2b(r);
        }

        asm volatile("s_waitcnt vmcnt(0)" ::: "memory");  // next chunk landed
        __syncthreads();                                  // all waves done with buf p
        p ^= 1;
    }
}

// ---------------------------------------------------------------------------
// Output kernel: out = tanh([reads | problems] Wo^T + bo), fp32 out
// K = 384 (256 reads bf16 + 128 problems fp32). grid (M_/128, 2) block 256
// ---------------------------------------------------------------------------
__global__ __launch_bounds__(256) void out_kernel(
    const unsigned short* __restrict__ reads,  // (M_,256) bf16
    const float* __restrict__ problems,        // (M_,128) fp32
    const float* __restrict__ Wo,              // (256,384) fp32
    const float* __restrict__ bo,              // (256) fp32
    float* __restrict__ out)                   // (M_,256) fp32
{
    constexpr int K = DV_ + DK_;  // 384
    const int mblk = blockIdx.x, nblk = blockIdx.y;

    __shared__ unsigned short As[128 * 40];
    __shared__ unsigned short Bs[128 * 40];

    const int tid  = threadIdx.x;
    const int lane = tid & 63, wid = tid >> 6;
    const int wm = wid >> 1, wn = wid & 1;
    const int l15 = lane & 15, quad = lane >> 4;

    float4v acc[4][4];
#pragma unroll
    for (int i = 0; i < 4; i++)
#pragma unroll
        for (int j = 0; j < 4; j++) {
            acc[i][j][0] = 0.f; acc[i][j][1] = 0.f;
            acc[i][j][2] = 0.f; acc[i][j][3] = 0.f;
        }

    const int srow = tid >> 1;
    const int scol = (tid & 1) * 16;
    const size_t mrow = (size_t)mblk * 128 + srow;
    const size_t brow = (size_t)nblk * 128 + srow;

    for (int k0 = 0; k0 < K; k0 += 32) {
        const int kk = k0 + scol;
        int4v a0, a1;
        if (kk < DV_) {  // reads, already bf16
            a0 = *(const int4v*)&reads[mrow * DV_ + kk];
            a1 = *(const int4v*)&reads[mrow * DV_ + kk + 8];
        } else {         // problems, fp32 -> bf16
            const float* pr = &problems[mrow * DK_ + (kk - DV_)];
#pragma unroll
            for (int j = 0; j < 4; j++) {
                a0[j] = pack2(pr[2*j],     pr[2*j + 1]);
                a1[j] = pack2(pr[2*j + 8], pr[2*j + 9]);
            }
        }
        const float* wb = &Wo[brow * K + kk];
        int4v b0, b1;
#pragma unroll
        for (int j = 0; j < 4; j++) {
            b0[j] = pack2(wb[2*j],     wb[2*j + 1]);
            b1[j] = pack2(wb[2*j + 8], wb[2*j + 9]);
        }
        *(int4v*)&As[srow * 40 + scol]     = a0;
        *(int4v*)&As[srow * 40 + scol + 8] = a1;
        *(int4v*)&Bs[srow * 40 + scol]     = b0;
        *(int4v*)&Bs[srow * 40 + scol + 8] = b1;
        __syncthreads();
        short8 af[4], bf[4];
#pragma unroll
        for (int i = 0; i < 4; i++)
            af[i] = *(const short8*)&As[(64 * wm + 16 * i + l15) * 40 + quad * 8];
#pragma unroll
        for (int j = 0; j < 4; j++)
            bf[j] = *(const short8*)&Bs[(64 * wn + 16 * j + l15) * 40 + quad * 8];
#pragma unroll
        for (int i = 0; i < 4; i++)
#pragma unroll
            for (int j = 0; j < 4; j++)
                acc[i][j] = __builtin_amdgcn_mfma_f32_16x16x32_bf16(af[i], bf[j], acc[i][j], 0, 0, 0);
        __syncthreads();
    }

#pragma unroll
    for (int i = 0; i < 4; i++) {
        const int row = mblk * 128 + 64 * wm + 16 * i + quad * 4;
#pragma unroll
        for (int j = 0; j < 4; j++) {
            const int col = nblk * 128 + 64 * wn + 16 * j + l15;
            const float bv = bo[col];
#pragma unroll
            for (int r = 0; r < 4; r++) {
                out[(size_t)(row + r) * H_ + col] = tanh_f(acc[i][j][r] + bv);
            }
        }
    }
}

// ---------------------------------------------------------------------------
extern "C" void kernel_launch(void* const* d_in, const int* in_sizes, int n_in,
                              void* d_out, int out_size, void* d_ws, size_t ws_size,
                              hipStream_t stream) {
    const float* problems  = (const float*)d_in[0];
    const float* interact  = (const float*)d_in[1];
    const float* w_key     = (const float*)d_in[2];
    const float* w_erase_w = (const float*)d_in[3];
    const float* w_erase_b = (const float*)d_in[4];
    const float* w_add_w   = (const float*)d_in[5];
    const float* w_add_b   = (const float*)d_in[6];
    const float* w_out_w   = (const float*)d_in[7];
    const float* w_out_b   = (const float*)d_in[8];
    const float* init_mem  = (const float*)d_in[9];

    // workspace: e (64MB bf16) | a (64MB bf16) | reads (64MB bf16) | score_scan (33.5MB fp32)
    char* ws = (char*)d_ws;
    const size_t SZ_BF = (size_t)M_ * DV_ * 2;   // 67,108,864
    unsigned short* e_buf = (unsigned short*)(ws);
    unsigned short* a_buf = (unsigned short*)(ws + SZ_BF);
    unsigned short* reads = (unsigned short*)(ws + 2 * SZ_BF);
    float*     score_scan = (float*)(ws + 3 * SZ_BF);

    gate_kernel<<<dim3(M_ / 128, DV_ / 128, 2), 256, 0, stream>>>(
        interact, w_erase_w, w_erase_b, w_add_w, w_add_b, e_buf, a_buf);

    score_kernel<<<M_ / 256, 256, 0, stream>>>(problems, w_key, score_scan);

    scan_kernel<<<dim3(4, B_), 256, 0, stream>>>(
        score_scan, e_buf, a_buf, init_mem, reads);

    out_kernel<<<dim3(M_ / 128, H_ / 128), 256, 0, stream>>>(
        reads, problems, w_out_w, w_out_b, (float*)d_out);
}